// Round 5
// baseline (422.946 us; speedup 1.0000x reference)
//
#include <hip/hip_runtime.h>
#include <math.h>

#define NL 12

typedef short v8s __attribute__((ext_vector_type(8)));
typedef float v4f __attribute__((ext_vector_type(4)));

struct PrepArgs {
  const float* in[40];
  void* out[40];
  int n[40];      // input element count
  int mode[40];   // 0 plain f32 fake-quant, 1 transposed f32 fake-quant, 2 conv int-bf16
  int tc[40];     // mode1: minor dim
  int ci[40], kk[40], kp[40], co[40];   // mode2 geometry
};

// power-of-two scale: 2^ceil(log2(max(maxv,1e-8)/levels)); f32 ratio (matches JAX),
// double log2/ceil so ceil lands on the right side of integer boundaries.
__device__ inline float p2_scale_f(float maxv, float levels) {
  float r = __fdiv_rn(fmaxf(maxv, 1e-8f), levels);
  return (float)exp2(ceil(log2((double)r)));
}

// blockDim must be 256. Result valid on thread 0. All threads must reach.
__device__ inline float block_reduce_max256(float v) {
  __shared__ float sm[4];
  #pragma unroll
  for (int off = 32; off; off >>= 1) v = fmaxf(v, __shfl_down(v, off));
  if ((threadIdx.x & 63) == 0) sm[threadIdx.x >> 6] = v;
  __syncthreads();
  if (threadIdx.x == 0) v = fmaxf(fmaxf(sm[0], sm[1]), fmaxf(sm[2], sm[3]));
  return v;
}

// v >= 0; non-negative float bits compare like unsigned. Read-skip cuts atomics.
__device__ inline void slot_max_update(float* slot, float v) {
  volatile unsigned int* su = (volatile unsigned int*)slot;
  unsigned int bits = __float_as_uint(v);
  if (bits > *su) atomicMax((unsigned int*)slot, bits);
}

// integer-valued float -> bf16 bits by truncation (exact for |v| <= 256)
__device__ inline ushort ibf16(float v) {
  return (ushort)(__float_as_uint(v) >> 16);
}

// blocks [0,40): per-tensor weight prep. blocks >=40: float4 grid-stride max of x.
__global__ void prep_kernel(PrepArgs a, float* wslot,
                            const float4* __restrict__ x4, int nx4, float* slot0) {
  if (blockIdx.x >= 40) {
    float m = 0.f;
    for (int i = (blockIdx.x - 40) * 256 + threadIdx.x; i < nx4; i += 256 * 256) {
      float4 v = x4[i];
      m = fmaxf(fmaxf(fmaxf(m, v.x), fmaxf(v.y, v.z)), v.w);
    }
    float bm = block_reduce_max256(m);
    if (threadIdx.x == 0) slot_max_update(slot0, bm);
    return;
  }
  __shared__ float ssc;
  const int t = blockIdx.x;
  const float* in = a.in[t];
  const int n = a.n[t], mode = a.mode[t];
  float m = 0.f;
  for (int i = threadIdx.x; i < n; i += 256) m = fmaxf(m, fabsf(in[i]));
  float bm = block_reduce_max256(m);
  if (threadIdx.x == 0) {
    ssc = p2_scale_f(bm, 127.0f);
    if (mode == 2) wslot[t] = ssc;
  }
  __syncthreads();
  const float s = ssc;
  if (mode == 2) {
    // conv weight: int codes as bf16, layout [Co][KP], k = khkw*Ci + ci, zero pad
    ushort* o = (ushort*)a.out[t];
    const int CI = a.ci[t], KK = a.kk[t], KP = a.kp[t], CO = a.co[t];
    const int KT = CI * KK;
    for (int i = threadIdx.x; i < CO * KP; i += 256) {
      int co = i / KP, k = i % KP;
      ushort v = 0;
      if (k < KT) {
        int khkw = k / CI, ci = k % CI;
        float q = rintf(__fdiv_rn(in[(co * CI + ci) * KK + khkw], s));
        q = fminf(fmaxf(q, -128.f), 127.f);
        v = ibf16(q);   // exact: |q| <= 128
      }
      o[i] = v;
    }
  } else {
    float* o = (float*)a.out[t];
    const int tc = a.tc[t];
    const int nw = (mode == 1) ? n / tc : 1;
    for (int i = threadIdx.x; i < n; i += 256) {
      float q = rintf(__fdiv_rn(in[i], s));
      q = fminf(fmaxf(q, -128.f), 127.f);
      float v = __fmul_rn(q, s);
      if (mode == 1) o[(i % nw) * tc + i / nw] = v;
      else o[i] = v;
    }
  }
}

// raw f32 activation -> bf16 integer codes (rint(v/s), s=2^e so mul is exact;
// 0 <= code <= 255 by scale construction; codes exact in bf16). n4 = n/4.
__global__ void pack_kernel(const float4* __restrict__ in, ushort* __restrict__ out,
                            int n4, const float* __restrict__ slot) {
  __shared__ float sinv;
  if (threadIdx.x == 0) sinv = __fdiv_rn(1.0f, p2_scale_f(slot[0], 255.0f));
  __syncthreads();
  const float inv = sinv;
  const int i = blockIdx.x * 256 + threadIdx.x;
  if (i < n4) {
    float4 v = in[i];
    ushort4 o;
    o.x = ibf16(rintf(__fmul_rn(v.x, inv)));
    o.y = ibf16(rintf(__fmul_rn(v.y, inv)));
    o.z = ibf16(rintf(__fmul_rn(v.z, inv)));
    o.w = ibf16(rintf(__fmul_rn(v.w, inv)));
    ((ushort4*)out)[i] = o;
  }
}

// ---------- MFMA implicit-GEMM conv ----------
// A = activation codes (pre-packed bf16 ints), B = weight codes. f32 MFMA
// accumulation exact (ints < 2^24). Epilogue: conv = acc*(s_in*s_w) [exact],
// y = conv*g + b (mul-then-add, matches XLA), relu, optional in-register 2x2
// max-pool, store raw f32 NHWC, track global max.

template <int CI, int H, int CO, bool K3, bool POOL>
__global__ __launch_bounds__(256)
void conv_mfma(const ushort* __restrict__ in, const ushort* __restrict__ wt,
               const float* __restrict__ sg, const float* __restrict__ sb,
               float* __restrict__ out, const float* __restrict__ slot_in,
               const float* __restrict__ wslotp, float* slot_out) {
  constexpr int W = H;
  constexpr int KT = (K3 ? 9 : 1) * CI;
  constexpr int SLABS = (KT + 31) / 32;
  constexpr int KP = SLABS * 32;
  constexpr int COT = CO / 16;
  constexpr int HO = POOL ? H / 2 : H;
  constexpr int WO = POOL ? W / 2 : W;
  static_assert(!K3 || CI == 16 || CI == 32, "K3 path assumes CI 16/32");

  const int lane = threadIdx.x & 63, widx = threadIdx.x >> 6;
  const int quad = lane >> 4, col = lane & 15;
  __builtin_assume(quad >= 0 && quad < 4);
  const float s_in = p2_scale_f(slot_in[0], 255.0f);
  const float S = __fmul_rn(s_in, wslotp[0]);   // exact: both 2^e
  const int wv = blockIdx.x * 4 + widx;

  int n, h, w, ph = 0, pw = 0;
  if constexpr (POOL) {
    constexpr int PB = (HO / 2) * (WO / 2);
    n = wv / PB; int r = wv % PB;
    ph = r / (WO / 2); pw = r % (WO / 2);
    h = 4 * ph + (col >> 2); w = 4 * pw + (col & 3);   // pre-pool 4x4 patch
  } else {
    int p = wv * 16 + col;
    n = p / (H * W); int r = p % (H * W);
    h = r / W; w = r % W;
  }
  const ushort* ibase = in + (size_t)n * H * W * CI;

  int toff[10]; bool tval[10];
  if constexpr (K3) {
    #pragma unroll
    for (int t = 0; t < 9; t++) {
      int kh = t / 3, kw = t % 3;
      int hh = h + kh - 1, ww = w + kw - 1;
      tval[t] = (hh >= 0) && (hh < H) && (ww >= 0) && (ww < W);
      toff[t] = (min(max(hh, 0), H - 1) * W + min(max(ww, 0), W - 1)) * CI;
    }
    toff[9] = toff[8]; tval[9] = false;   // pad-K lanes land here
  }

  v4f acc[COT];
  #pragma unroll
  for (int c = 0; c < COT; c++) acc[c] = (v4f){0.f, 0.f, 0.f, 0.f};
  const v8s zv = {0, 0, 0, 0, 0, 0, 0, 0};

  #pragma unroll
  for (int slab = 0; slab < SLABS; slab++) {
    v8s a;
    if constexpr (K3) {
      int tof; bool tv;
      int cib;
      if constexpr (CI == 32) {            // one tap per slab
        tof = toff[slab]; tv = tval[slab]; cib = quad * 8;
      } else {                             // CI==16: two taps per slab
        const bool hi = (quad & 2) != 0;
        tof = hi ? toff[2 * slab + 1] : toff[2 * slab];
        tv  = hi ? tval[2 * slab + 1] : tval[2 * slab];
        cib = (quad & 1) * 8;
      }
      v8s av = *(const v8s*)(ibase + tof + cib);
      a = tv ? av : zv;
    } else {
      const int cib = (slab * 32 + quad * 8) % CI;  // wraps on pad quads (x zero wts)
      a = *(const v8s*)(ibase + (size_t)(h * W + w) * CI + cib);
    }
    #pragma unroll
    for (int c = 0; c < COT; c++) {
      v8s b = *(const v8s*)(wt + (size_t)(c * 16 + col) * KP + slab * 32 + quad * 8);
      acc[c] = __builtin_amdgcn_mfma_f32_16x16x32_bf16(a, b, acc[c], 0, 0, 0);
    }
  }

  float zmax = 0.f;
  #pragma unroll
  for (int c = 0; c < COT; c++) {
    const int cog = c * 16 + col;
    const float g = sg[cog], bb = sb[cog];
    float z[4];
    #pragma unroll
    for (int r2 = 0; r2 < 4; r2++) {
      float t = __fmul_rn(acc[c][r2], S);                       // exact
      z[r2] = fmaxf(__fadd_rn(__fmul_rn(t, g), bb), 0.f);       // matches XLA
    }
    if constexpr (POOL) {
      float h0 = fmaxf(z[0], z[1]), h1 = fmaxf(z[2], z[3]);
      float o0 = fmaxf(h0, __shfl_xor(h0, 16));
      float o1 = fmaxf(h1, __shfl_xor(h1, 16));
      zmax = fmaxf(zmax, fmaxf(o0, o1));
      if (!(quad & 1)) {   // quads 0,2 own pooled rows 0,1
        int oh = 2 * ph + (quad >> 1), ow = 2 * pw;
        float* op = out + ((size_t)((n * HO + oh) * WO + ow)) * CO + cog;
        op[0] = o0; op[CO] = o1;
      }
    } else {
      const int pbase = wv * 16 + quad * 4;
      #pragma unroll
      for (int r2 = 0; r2 < 4; r2++) {
        out[(size_t)(pbase + r2) * CO + cog] = z[r2];
        zmax = fmaxf(zmax, z[r2]);
      }
    }
  }
  float bm = block_reduce_max256(zmax);
  if (threadIdx.x == 0) slot_max_update(slot_out, bm);
}

// conv1: NCHW input CODES (ushort), Ci=3, K=27 padded to 32 (one slab),
// CO=32, pool 224->112. Per-lane scalar ushort gather.
__global__ __launch_bounds__(256)
void conv1_mfma(const ushort* __restrict__ xc, const ushort* __restrict__ wt,
                const float* __restrict__ sg, const float* __restrict__ sb,
                float* __restrict__ out, const float* __restrict__ slot_in,
                const float* __restrict__ wslotp, float* slot_out) {
  const int lane = threadIdx.x & 63, widx = threadIdx.x >> 6;
  const int quad = lane >> 4, col = lane & 15;
  const float s_in = p2_scale_f(slot_in[0], 255.0f);
  const float S = __fmul_rn(s_in, wslotp[0]);
  const int wv = blockIdx.x * 4 + widx;
  const int n = wv / 3136, r = wv % 3136;
  const int ph = r / 56, pw = r % 56;
  const int h = 4 * ph + (col >> 2), w = 4 * pw + (col & 3);

  v8s a;
  #pragma unroll
  for (int j = 0; j < 8; j++) {
    int k = quad * 8 + j;
    int kc = min(k, 26);
    int khkw = kc / 3, ci = kc - khkw * 3;
    int kh = khkw / 3, kw = khkw - kh * 3;
    int hh = h + kh - 1, ww = w + kw - 1;
    bool valid = (k < 27) && (hh >= 0) && (hh < 224) && (ww >= 0) && (ww < 224);
    int hc = min(max(hh, 0), 223), wc = min(max(ww, 0), 223);
    ushort v = xc[((n * 3 + ci) * 224 + hc) * 224 + wc];
    a[j] = valid ? (short)v : (short)0;
  }
  v4f acc[2];
  acc[0] = (v4f){0.f, 0.f, 0.f, 0.f};
  acc[1] = acc[0];
  #pragma unroll
  for (int c = 0; c < 2; c++) {
    v8s b = *(const v8s*)(wt + (size_t)(c * 16 + col) * 32 + quad * 8);
    acc[c] = __builtin_amdgcn_mfma_f32_16x16x32_bf16(a, b, acc[c], 0, 0, 0);
  }
  float zmax = 0.f;
  #pragma unroll
  for (int c = 0; c < 2; c++) {
    const int cog = c * 16 + col;
    const float g = sg[cog], bb = sb[cog];
    float z[4];
    #pragma unroll
    for (int r2 = 0; r2 < 4; r2++) {
      float t = __fmul_rn(acc[c][r2], S);
      z[r2] = fmaxf(__fadd_rn(__fmul_rn(t, g), bb), 0.f);
    }
    float h0 = fmaxf(z[0], z[1]), h1 = fmaxf(z[2], z[3]);
    float o0 = fmaxf(h0, __shfl_xor(h0, 16));
    float o1 = fmaxf(h1, __shfl_xor(h1, 16));
    zmax = fmaxf(zmax, fmaxf(o0, o1));
    if (!(quad & 1)) {
      int oh = 2 * ph + (quad >> 1), ow = 2 * pw;
      float* op = out + ((size_t)((n * 112 + oh) * 112 + ow)) * 32 + cog;
      op[0] = o0; op[32] = o1;
    }
  }
  float bm = block_reduce_max256(zmax);
  if (threadIdx.x == 0) slot_max_update(slot_out, bm);
}

// NHWC avgpool: in [16][784][64] raw; quantize on read, exact sum, one divide.
__global__ void avgpool_kernel(const float* __restrict__ in, float* __restrict__ out,
                               const float* __restrict__ slot_in, float* slot_out) {
  __shared__ float red[256];
  const float s = p2_scale_f(slot_in[0], 255.0f);
  const float inv = __fdiv_rn(1.0f, s);
  const int nn = blockIdx.x, co = threadIdx.x & 63, part = threadIdx.x >> 6;
  const float* p = in + (size_t)nn * 784 * 64;
  float sum = 0.f;
  for (int i = part * 196; i < part * 196 + 196; i++)
    sum += __fmul_rn(rintf(__fmul_rn(p[i * 64 + co], inv)), s);
  red[threadIdx.x] = sum;
  __syncthreads();
  if (threadIdx.x < 64) {
    float tot = (red[co] + red[64 + co]) + (red[128 + co] + red[192 + co]);
    float m = __fdiv_rn(tot, 784.0f);
    out[nn * 64 + co] = m;
    slot_max_update(slot_out, m);
  }
}

// quant(mean) -> fc1 -> relu -> quant -> fc2, one 256-thread block.
__global__ void tail_kernel(const float* __restrict__ pooled,
                            const float* __restrict__ fw1, const float* __restrict__ fb1,
                            const float* __restrict__ fw2, const float* __restrict__ fb2,
                            const float* __restrict__ slot_in, float* __restrict__ out) {
  __shared__ float xq[1024];
  __shared__ float hq[256];
  __shared__ float s2s;
  const int t = threadIdx.x;
  const float s = p2_scale_f(slot_in[0], 255.0f);
  const float inv = __fdiv_rn(1.0f, s);
  for (int i = t; i < 1024; i += 256)
    xq[i] = __fmul_rn(rintf(__fmul_rn(pooled[i], inv)), s);
  __syncthreads();
  const int n = t >> 4, j = t & 15;
  float acc = 0.f;
  #pragma unroll 8
  for (int k = 0; k < 64; k++) acc += xq[n * 64 + k] * fw1[k * 16 + j];  // exact
  float z = fmaxf(__fadd_rn(acc, fb1[j]), 0.f);
  float bm = block_reduce_max256(z);
  if (t == 0) s2s = p2_scale_f(bm, 255.0f);
  __syncthreads();
  const float s2 = s2s, inv2 = __fdiv_rn(1.0f, s2);
  hq[t] = __fmul_rn(rintf(__fmul_rn(z, inv2)), s2);
  __syncthreads();
  if (t < 160) {
    const int n2 = t / 10, j2 = t % 10;
    float a2 = 0.f;
    #pragma unroll
    for (int k = 0; k < 16; k++) a2 += hq[n2 * 16 + k] * fw2[k * 10 + j2];  // exact
    out[t] = __fadd_rn(a2, fb2[j2]);
  }
}

extern "C" void kernel_launch(void* const* d_in, const int* in_sizes, int n_in,
                              void* d_out, int out_size, void* d_ws, size_t ws_size,
                              hipStream_t stream) {
  static const int h_ci[NL] = {3, 32, 16, 16, 32, 32, 64, 32, 64, 32, 64, 32};
  static const int h_co[NL] = {32, 16, 16, 32, 32, 64, 32, 64, 32, 64, 32, 64};
  static const int h_kk[NL] = {9, 9, 1, 9, 1, 9, 1, 9, 1, 9, 1, 9};
  static const int h_kp[NL] = {32, 288, 32, 160, 32, 288, 64, 288, 64, 288, 64, 288};

  float* ws = (float*)d_ws;
  float* slots = ws;                 // [0..13] activation-max slots
  float* wslot = ws + 16;            // [0..11] conv weight scales
  size_t off = 32;

  ushort* wq[NL];
  for (int l = 0; l < NL; l++) {
    wq[l] = (ushort*)(ws + off);
    off += (size_t)(h_co[l] * h_kp[l]) / 2;   // shorts -> floats (all even, /4 ok)
  }
  float* sgq[NL]; float* sbq[NL];
  for (int l = 0; l < NL; l++) { sgq[l] = ws + off; off += 64; }
  for (int l = 0; l < NL; l++) { sbq[l] = ws + off; off += 64; }
  float* fw1q = ws + off; off += 1024;
  float* fb1q = ws + off; off += 16;
  float* fw2q = ws + off; off += 160;
  float* fb2q = ws + off; off += 16;
  float* rawA = ws + off; off += 6422528;   // NHWC raw ping (max: conv1 out)
  float* rawB = ws + off; off += 1605632;   // NHWC raw pong (max: conv32 out)
  ushort* C  = (ushort*)(ws + off); off += 3211264;  // code buffer (max 6.42M elems)
  float* P = ws + off; off += 1024;         // pooled means [16][64]

  PrepArgs pa;
  for (int l = 0; l < NL; l++) {
    pa.in[l] = (const float*)d_in[1 + 3 * l]; pa.out[l] = (void*)wq[l];
    pa.n[l] = h_co[l] * h_ci[l] * h_kk[l];
    pa.mode[l] = 2; pa.tc[l] = 0;
    pa.ci[l] = h_ci[l]; pa.kk[l] = h_kk[l]; pa.kp[l] = h_kp[l]; pa.co[l] = h_co[l];
    pa.in[12 + l] = (const float*)d_in[2 + 3 * l]; pa.out[12 + l] = (void*)sgq[l];
    pa.n[12 + l] = h_co[l]; pa.mode[12 + l] = 0; pa.tc[12 + l] = 0;
    pa.ci[12 + l] = pa.kk[12 + l] = pa.kp[12 + l] = pa.co[12 + l] = 0;
    pa.in[24 + l] = (const float*)d_in[3 + 3 * l]; pa.out[24 + l] = (void*)sbq[l];
    pa.n[24 + l] = h_co[l]; pa.mode[24 + l] = 0; pa.tc[24 + l] = 0;
    pa.ci[24 + l] = pa.kk[24 + l] = pa.kp[24 + l] = pa.co[24 + l] = 0;
  }
  pa.in[36] = (const float*)d_in[37]; pa.out[36] = (void*)fw1q;
  pa.n[36] = 1024; pa.mode[36] = 1; pa.tc[36] = 16;
  pa.ci[36] = pa.kk[36] = pa.kp[36] = pa.co[36] = 0;
  pa.in[37] = (const float*)d_in[38]; pa.out[37] = (void*)fb1q;
  pa.n[37] = 16; pa.mode[37] = 0; pa.tc[37] = 0;
  pa.ci[37] = pa.kk[37] = pa.kp[37] = pa.co[37] = 0;
  pa.in[38] = (const float*)d_in[39]; pa.out[38] = (void*)fw2q;
  pa.n[38] = 160; pa.mode[38] = 1; pa.tc[38] = 10;
  pa.ci[38] = pa.kk[38] = pa.kp[38] = pa.co[38] = 0;
  pa.in[39] = (const float*)d_in[40]; pa.out[39] = (void*)fb2q;
  pa.n[39] = 10; pa.mode[39] = 0; pa.tc[39] = 0;
  pa.ci[39] = pa.kk[39] = pa.kp[39] = pa.co[39] = 0;

  const float* x = (const float*)d_in[0];
  const int nx4 = 16 * 3 * 224 * 224 / 4;   // 602112

  hipMemsetAsync(slots, 0, 16 * sizeof(float), stream);
  prep_kernel<<<40 + 256, 256, 0, stream>>>(pa, wslot, (const float4*)x, nx4, slots + 0);

  pack_kernel<<<2352, 256, 0, stream>>>((const float4*)x, C, nx4, slots + 0);
  conv1_mfma<<<12544, 256, 0, stream>>>(C, wq[0], sgq[0], sbq[0], rawA,
                                        slots + 0, wslot + 0, slots + 1);

  pack_kernel<<<6272, 256, 0, stream>>>((const float4*)rawA, C, 1605632, slots + 1);
  conv_mfma<32, 112, 16, true, true><<<3136, 256, 0, stream>>>(
      C, wq[1], sgq[1], sbq[1], rawB, slots + 1, wslot + 1, slots + 2);

  pack_kernel<<<784, 256, 0, stream>>>((const float4*)rawB, C, 200704, slots + 2);
  conv_mfma<16, 56, 16, false, false><<<784, 256, 0, stream>>>(
      C, wq[2], sgq[2], sbq[2], rawA, slots + 2, wslot + 2, slots + 3);

  pack_kernel<<<784, 256, 0, stream>>>((const float4*)rawA, C, 200704, slots + 3);
  conv_mfma<16, 56, 32, true, false><<<784, 256, 0, stream>>>(
      C, wq[3], sgq[3], sbq[3], rawB, slots + 3, wslot + 3, slots + 4);

  pack_kernel<<<1568, 256, 0, stream>>>((const float4*)rawB, C, 401408, slots + 4);
  conv_mfma<32, 56, 32, false, false><<<784, 256, 0, stream>>>(
      C, wq[4], sgq[4], sbq[4], rawA, slots + 4, wslot + 4, slots + 5);

  pack_kernel<<<1568, 256, 0, stream>>>((const float4*)rawA, C, 401408, slots + 5);
  conv_mfma<32, 56, 64, true, true><<<784, 256, 0, stream>>>(
      C, wq[5], sgq[5], sbq[5], rawB, slots + 5, wslot + 5, slots + 6);

  pack_kernel<<<784, 256, 0, stream>>>((const float4*)rawB, C, 200704, slots + 6);
  conv_mfma<64, 28, 32, false, false><<<196, 256, 0, stream>>>(
      C, wq[6], sgq[6], sbq[6], rawA, slots + 6, wslot + 6, slots + 7);

  pack_kernel<<<392, 256, 0, stream>>>((const float4*)rawA, C, 100352, slots + 7);
  conv_mfma<32, 28, 64, true, false><<<196, 256, 0, stream>>>(
      C, wq[7], sgq[7], sbq[7], rawB, slots + 7, wslot + 7, slots + 8);

  pack_kernel<<<784, 256, 0, stream>>>((const float4*)rawB, C, 200704, slots + 8);
  conv_mfma<64, 28, 32, false, false><<<196, 256, 0, stream>>>(
      C, wq[8], sgq[8], sbq[8], rawA, slots + 8, wslot + 8, slots + 9);

  pack_kernel<<<392, 256, 0, stream>>>((const float4*)rawA, C, 100352, slots + 9);
  conv_mfma<32, 28, 64, true, false><<<196, 256, 0, stream>>>(
      C, wq[9], sgq[9], sbq[9], rawB, slots + 9, wslot + 9, slots + 10);

  pack_kernel<<<784, 256, 0, stream>>>((const float4*)rawB, C, 200704, slots + 10);
  conv_mfma<64, 28, 32, false, false><<<196, 256, 0, stream>>>(
      C, wq[10], sgq[10], sbq[10], rawA, slots + 10, wslot + 10, slots + 11);

  pack_kernel<<<392, 256, 0, stream>>>((const float4*)rawA, C, 100352, slots + 11);
  conv_mfma<32, 28, 64, true, false><<<196, 256, 0, stream>>>(
      C, wq[11], sgq[11], sbq[11], rawB, slots + 11, wslot + 11, slots + 12);

  avgpool_kernel<<<16, 256, 0, stream>>>(rawB, P, slots + 12, slots + 13);
  tail_kernel<<<1, 256, 0, stream>>>(P, fw1q, fb1q, fw2q, fb2q, slots + 13,
                                     (float*)d_out);
}